// Round 3
// baseline (3288.314 us; speedup 1.0000x reference)
//
#include <hip/hip_runtime.h>
#include <hip/hip_bf16.h>
#include <math.h>

typedef __bf16 bf16;
typedef __bf16 bf16x8 __attribute__((ext_vector_type(8)));
typedef float f32x4 __attribute__((ext_vector_type(4)));

#define SEQ 1024
#define DMODEL 1024

// ---------------------------------------------------------------------------
// Fused transpose + fp32->bf16 convert: out[n*K + k] = (bf16)in[k*N + n]
// ---------------------------------------------------------------------------
__global__ void transpose_f2b(const float* __restrict__ in, bf16* __restrict__ out,
                              int K, int N) {
    __shared__ float tile[32][33];
    int n0 = blockIdx.x * 32, k0 = blockIdx.y * 32;
    int tx = threadIdx.x, ty = threadIdx.y;
#pragma unroll
    for (int i = 0; i < 4; ++i) {
        int kk = ty + i * 8;
        tile[kk][tx] = in[(size_t)(k0 + kk) * N + n0 + tx];
    }
    __syncthreads();
#pragma unroll
    for (int i = 0; i < 4; ++i) {
        int nn = ty + i * 8;
        out[(size_t)(n0 + nn) * K + k0 + tx] = (bf16)tile[tx][nn];
    }
}

// ---------------------------------------------------------------------------
// LayerNorm: fp32 in -> bf16 out. One row (D=1024) per 256-thread block.
// ---------------------------------------------------------------------------
__global__ void ln_f2b(const float* __restrict__ x, const float* __restrict__ g,
                       const float* __restrict__ bta, bf16* __restrict__ y) {
    int row = blockIdx.x, t = threadIdx.x;
    const float* xr = x + (size_t)row * DMODEL;
    float v[4];
#pragma unroll
    for (int i = 0; i < 4; ++i) v[i] = xr[t * 4 + i];
    float s = v[0] + v[1] + v[2] + v[3];
    float s2 = v[0] * v[0] + v[1] * v[1] + v[2] * v[2] + v[3] * v[3];
#pragma unroll
    for (int off = 32; off > 0; off >>= 1) {
        s += __shfl_down(s, off, 64);
        s2 += __shfl_down(s2, off, 64);
    }
    __shared__ float ws1[4], ws2[4];
    __shared__ float mu_s, rstd_s;
    int lane = t & 63, wv = t >> 6;
    if (lane == 0) { ws1[wv] = s; ws2[wv] = s2; }
    __syncthreads();
    if (t == 0) {
        float S1 = ws1[0] + ws1[1] + ws1[2] + ws1[3];
        float S2 = ws2[0] + ws2[1] + ws2[2] + ws2[3];
        float mu = S1 * (1.0f / DMODEL);
        float var = S2 * (1.0f / DMODEL) - mu * mu;
        mu_s = mu;
        rstd_s = rsqrtf(var + 1e-5f);
    }
    __syncthreads();
    float mu = mu_s, rstd = rstd_s;
    bf16* yr = y + (size_t)row * DMODEL;
#pragma unroll
    for (int i = 0; i < 4; ++i) {
        int d = t * 4 + i;
        float o = (v[i] - mu) * rstd * g[d] + bta[d];
        yr[d] = (bf16)o;
    }
}

// ---------------------------------------------------------------------------
// GEMM: C[M,N] = A[M,K](bf16) @ Bt[N,K](bf16)^T + bias(fp32)
// mode: 0 = bf16 out, 1 = bf16 out + exact GELU, 2 = fp32 out
// 128x128 tile, BK=32, 4 waves 2x2, 4x4 MFMA 16x16x32 per wave
// A/B frag: m(n)=lane&15, k=(lane>>4)*8+j ; C/D: col=lane&15, row=(lane>>4)*4+reg
// ---------------------------------------------------------------------------
#define BM 128
#define BN 128
#define BK 32
#define LDT 40

__global__ __launch_bounds__(256, 2) void gemm_bt(
    const bf16* __restrict__ A, const bf16* __restrict__ Bt,
    const float* __restrict__ bias, void* __restrict__ Cv,
    int M, int N, int K, int mode) {
    __shared__ bf16 sA[BM][LDT];
    __shared__ bf16 sB[BN][LDT];
    int t = threadIdx.x;
    int lane = t & 63, wave = t >> 6;
    int wr = wave >> 1, wc = wave & 1;
    int m0 = blockIdx.y * BM, n0 = blockIdx.x * BN;
    int ar = t >> 2;
    int ak = (t & 3) * 8;
    const bf16* Ap = A + (size_t)m0 * K;
    const bf16* Bp = Bt + (size_t)n0 * K;

    f32x4 acc[4][4];
#pragma unroll
    for (int i = 0; i < 4; ++i)
#pragma unroll
        for (int j = 0; j < 4; ++j) acc[i][j] = (f32x4){0.f, 0.f, 0.f, 0.f};

    int mq = lane & 15, kq = (lane >> 4) * 8;

    for (int k0 = 0; k0 < K; k0 += BK) {
        __syncthreads();
        *(uint4*)&sA[ar][ak]      = *(const uint4*)(Ap + (size_t)ar * K + k0 + ak);
        *(uint4*)&sA[ar + 64][ak] = *(const uint4*)(Ap + (size_t)(ar + 64) * K + k0 + ak);
        *(uint4*)&sB[ar][ak]      = *(const uint4*)(Bp + (size_t)ar * K + k0 + ak);
        *(uint4*)&sB[ar + 64][ak] = *(const uint4*)(Bp + (size_t)(ar + 64) * K + k0 + ak);
        __syncthreads();
        bf16x8 af[4], bfr[4];
#pragma unroll
        for (int i = 0; i < 4; ++i)
            af[i] = *(const bf16x8*)&sA[wr * 64 + i * 16 + mq][kq];
#pragma unroll
        for (int j = 0; j < 4; ++j)
            bfr[j] = *(const bf16x8*)&sB[wc * 64 + j * 16 + mq][kq];
#pragma unroll
        for (int i = 0; i < 4; ++i)
#pragma unroll
            for (int j = 0; j < 4; ++j)
                acc[i][j] = __builtin_amdgcn_mfma_f32_16x16x32_bf16(af[i], bfr[j], acc[i][j], 0, 0, 0);
    }

    int cq = lane & 15, rq = (lane >> 4) * 4;
#pragma unroll
    for (int i = 0; i < 4; ++i) {
        int row = m0 + wr * 64 + i * 16 + rq;
#pragma unroll
        for (int j = 0; j < 4; ++j) {
            int col = n0 + wc * 64 + j * 16 + cq;
            float bv = bias ? bias[col] : 0.0f;
#pragma unroll
            for (int r = 0; r < 4; ++r) {
                float v = acc[i][j][r] + bv;
                if (mode == 1) v = 0.5f * v * (1.0f + erff(v * 0.70710678118654752f));
                size_t idx = (size_t)(row + r) * N + col;
                if (mode == 2) ((float*)Cv)[idx] = v;
                else           ((bf16*)Cv)[idx] = (bf16)v;
            }
        }
    }
}

// ---------------------------------------------------------------------------
// Attention: per block = 8 Q rows of one (b,h); two-pass softmax, S in LDS.
// qkv (bf16) layout [B, N, 3*1024]: q col h*64+d, k 1024+h*64+d, v 2048+...
// ---------------------------------------------------------------------------
__global__ __launch_bounds__(256) void attn_kernel(const bf16* __restrict__ qkv,
                                                   bf16* __restrict__ ao) {
    __shared__ float S[8][SEQ];
    __shared__ float KV[64][65];
    __shared__ float Qs[8][65];
    __shared__ float rsum[8];
    int t = threadIdx.x;
    int bh = blockIdx.y, bb = bh >> 4, h = bh & 15;
    int q0 = blockIdx.x * 8;
    const bf16* base = qkv + (size_t)bb * SEQ * 3072;

    if (t < 64) {
        int q = t >> 3, d0 = (t & 7) * 8;
        const bf16* p = base + (size_t)(q0 + q) * 3072 + h * 64 + d0;
#pragma unroll
        for (int i = 0; i < 8; ++i) Qs[q][d0 + i] = (float)p[i] * 0.125f;
    }
    int kk = t & 63, qg = t >> 6;
    int skey = t >> 3, sd0 = (t & 7) * 8;

    for (int kt = 0; kt < 16; ++kt) {
        __syncthreads();
#pragma unroll
        for (int s = 0; s < 2; ++s) {
            int key = skey + s * 32;
            const bf16* p = base + (size_t)(kt * 64 + key) * 3072 + 1024 + h * 64 + sd0;
#pragma unroll
            for (int i = 0; i < 8; ++i) KV[sd0 + i][key] = (float)p[i];
        }
        __syncthreads();
#pragma unroll
        for (int s = 0; s < 2; ++s) {
            int q = qg * 2 + s;
            float acc = 0.f;
#pragma unroll
            for (int d = 0; d < 64; ++d) acc += Qs[q][d] * KV[d][kk];
            S[q][kt * 64 + kk] = acc;
        }
    }
    __syncthreads();

    {
        int r = t >> 5, jj = t & 31;
        float mx = -1e30f;
        for (int j = jj; j < SEQ; j += 32) mx = fmaxf(mx, S[r][j]);
#pragma unroll
        for (int off = 16; off > 0; off >>= 1) mx = fmaxf(mx, __shfl_down(mx, off, 32));
        mx = __shfl(mx, 0, 32);
        float sum = 0.f;
        for (int j = jj; j < SEQ; j += 32) {
            float e = __expf(S[r][j] - mx);
            S[r][j] = e;
            sum += e;
        }
#pragma unroll
        for (int off = 16; off > 0; off >>= 1) sum += __shfl_down(sum, off, 32);
        if (jj == 0) rsum[r] = 1.0f / sum;
    }

    int d = t & 63, qg2 = t >> 6;
    float o0 = 0.f, o1 = 0.f;
    for (int kt = 0; kt < 16; ++kt) {
        __syncthreads();
#pragma unroll
        for (int s = 0; s < 2; ++s) {
            int key = skey + s * 32;
            const bf16* p = base + (size_t)(kt * 64 + key) * 3072 + 2048 + h * 64 + sd0;
#pragma unroll
            for (int i = 0; i < 8; ++i) KV[key][sd0 + i] = (float)p[i];
        }
        __syncthreads();
#pragma unroll
        for (int j = 0; j < 64; ++j) {
            float v = KV[j][d];
            o0 += S[qg2 * 2][kt * 64 + j] * v;
            o1 += S[qg2 * 2 + 1][kt * 64 + j] * v;
        }
    }
    int q = qg2 * 2;
    ao[((size_t)bb * SEQ + q0 + q) * DMODEL + h * 64 + d] = (bf16)(o0 * rsum[q]);
    ao[((size_t)bb * SEQ + q0 + q + 1) * DMODEL + h * 64 + d] = (bf16)(o1 * rsum[q + 1]);
}

// ---------------------------------------------------------------------------
// kernel_launch — fp32 I/O, bf16 internal. ws peak 56 MiB; d_out (32 MB) used
// as scratch for sequential 16-MB tenants.
//   ws[0,6):  wqkvT bf16        (live: until QKV gemm)
//   ws[6,8):  woutT bf16        (live: until out-proj)
//   ws[8,56): qkv bf16          (live: QKV gemm -> attn)
//   ws[8,16): w1T bf16          (written after attn, over dead qkv)
//   ws[16,24): w2T bf16         (same)
//   ws[24,56): x2 fp32          (out-proj -> ln2; over dead qkv)
//   ws[24,56): h chunk bf16 4096x4096 (mlp1 -> mlp2; over dead x2)
//   d_out[0,16M):  xn bf16 -> ao bf16 (sequential)
//   d_out[16M,32M): x2n bf16
//   d_out[0,32M): final fp32 out (mlp2 c0 writes [0,16M) after x2n rows
//                 [0,4096) consumed; c1 writes [16M,32M) after its read)
// ---------------------------------------------------------------------------
extern "C" void kernel_launch(void* const* d_in, const int* in_sizes, int n_in,
                              void* d_out, int out_size, void* d_ws, size_t ws_size,
                              hipStream_t stream) {
    const float* x     = (const float*)d_in[0];
    const float* ln1_g = (const float*)d_in[1];
    const float* ln1_b = (const float*)d_in[2];
    const float* w_qkv = (const float*)d_in[3];
    const float* w_out = (const float*)d_in[4];
    const float* b_out = (const float*)d_in[5];
    const float* ln2_g = (const float*)d_in[6];
    const float* ln2_b = (const float*)d_in[7];
    const float* w1    = (const float*)d_in[8];
    const float* b1    = (const float*)d_in[9];
    const float* w2    = (const float*)d_in[10];
    const float* b2    = (const float*)d_in[11];
    float* out = (float*)d_out;
    char* ws = (char*)d_ws;
    char* outc = (char*)d_out;

    bf16* wqkvT = (bf16*)(ws + (0ull << 20));
    bf16* woutT = (bf16*)(ws + (6ull << 20));
    bf16* qkv   = (bf16*)(ws + (8ull << 20));
    bf16* w1T   = (bf16*)(ws + (8ull << 20));    // over dead qkv (after attn)
    bf16* w2T   = (bf16*)(ws + (16ull << 20));   // over dead qkv (after attn)
    float* x2   = (float*)(ws + (24ull << 20));  // over dead qkv (after attn)
    bf16* hbuf  = (bf16*)(ws + (24ull << 20));   // over dead x2 (after ln2)
    bf16* xn    = (bf16*)(outc + 0);             // d_out as scratch
    bf16* ao    = (bf16*)(outc + 0);             // xn dead
    bf16* x2n   = (bf16*)(outc + (16ull << 20)); // upper half of d_out

    dim3 tb(32, 8);
    transpose_f2b<<<dim3(3072 / 32, 1024 / 32), tb, 0, stream>>>(w_qkv, wqkvT, 1024, 3072);
    transpose_f2b<<<dim3(1024 / 32, 1024 / 32), tb, 0, stream>>>(w_out, woutT, 1024, 1024);

    ln_f2b<<<8192, 256, 0, stream>>>(x, ln1_g, ln1_b, xn);
    gemm_bt<<<dim3(3072 / 128, 8192 / 128), 256, 0, stream>>>(xn, wqkvT, nullptr, qkv,
                                                              8192, 3072, 1024, 0);
    attn_kernel<<<dim3(128, 128), 256, 0, stream>>>(qkv, ao);

    transpose_f2b<<<dim3(4096 / 32, 1024 / 32), tb, 0, stream>>>(w1, w1T, 1024, 4096);
    transpose_f2b<<<dim3(1024 / 32, 4096 / 32), tb, 0, stream>>>(w2, w2T, 4096, 1024);

    gemm_bt<<<dim3(1024 / 128, 8192 / 128), 256, 0, stream>>>(ao, woutT, b_out, x2,
                                                              8192, 1024, 1024, 2);
    ln_f2b<<<8192, 256, 0, stream>>>(x2, ln2_g, ln2_b, x2n);

    for (int c = 0; c < 2; ++c) {
        const bf16* a1 = x2n + (size_t)c * 4096 * 1024;
        float* oc = out + (size_t)c * 4096 * 1024;
        gemm_bt<<<dim3(4096 / 128, 4096 / 128), 256, 0, stream>>>(a1, w1T, b1, hbuf,
                                                                  4096, 4096, 1024, 1);
        gemm_bt<<<dim3(1024 / 128, 4096 / 128), 256, 0, stream>>>(hbuf, w2T, b2, oc,
                                                                  4096, 1024, 4096, 2);
    }
}

// Round 4
// 700.430 us; speedup vs baseline: 4.6947x; 4.6947x over previous
//
#include <hip/hip_runtime.h>
#include <hip/hip_bf16.h>
#include <math.h>

typedef __bf16 bf16;
typedef __bf16 bf16x8 __attribute__((ext_vector_type(8)));
typedef float f32x4 __attribute__((ext_vector_type(4)));

#define SEQ 1024
#define DMODEL 1024

// ---------------------------------------------------------------------------
// Fused transpose + fp32->bf16 convert: out[n*K + k] = (bf16)in[k*N + n]
// ---------------------------------------------------------------------------
__global__ void transpose_f2b(const float* __restrict__ in, bf16* __restrict__ out,
                              int K, int N) {
    __shared__ float tile[32][33];
    int n0 = blockIdx.x * 32, k0 = blockIdx.y * 32;
    int tx = threadIdx.x, ty = threadIdx.y;
#pragma unroll
    for (int i = 0; i < 4; ++i) {
        int kk = ty + i * 8;
        tile[kk][tx] = in[(size_t)(k0 + kk) * N + n0 + tx];
    }
    __syncthreads();
#pragma unroll
    for (int i = 0; i < 4; ++i) {
        int nn = ty + i * 8;
        out[(size_t)(n0 + nn) * K + k0 + tx] = (bf16)tile[tx][nn];
    }
}

// ---------------------------------------------------------------------------
// LayerNorm: fp32 in -> bf16 out. One row (D=1024) per 256-thread block.
// ---------------------------------------------------------------------------
__global__ void ln_f2b(const float* __restrict__ x, const float* __restrict__ g,
                       const float* __restrict__ bta, bf16* __restrict__ y) {
    int row = blockIdx.x, t = threadIdx.x;
    const float* xr = x + (size_t)row * DMODEL;
    float v[4];
#pragma unroll
    for (int i = 0; i < 4; ++i) v[i] = xr[t * 4 + i];
    float s = v[0] + v[1] + v[2] + v[3];
    float s2 = v[0] * v[0] + v[1] * v[1] + v[2] * v[2] + v[3] * v[3];
#pragma unroll
    for (int off = 32; off > 0; off >>= 1) {
        s += __shfl_down(s, off, 64);
        s2 += __shfl_down(s2, off, 64);
    }
    __shared__ float ws1[4], ws2[4];
    __shared__ float mu_s, rstd_s;
    int lane = t & 63, wv = t >> 6;
    if (lane == 0) { ws1[wv] = s; ws2[wv] = s2; }
    __syncthreads();
    if (t == 0) {
        float S1 = ws1[0] + ws1[1] + ws1[2] + ws1[3];
        float S2 = ws2[0] + ws2[1] + ws2[2] + ws2[3];
        float mu = S1 * (1.0f / DMODEL);
        float var = S2 * (1.0f / DMODEL) - mu * mu;
        mu_s = mu;
        rstd_s = rsqrtf(var + 1e-5f);
    }
    __syncthreads();
    float mu = mu_s, rstd = rstd_s;
    bf16* yr = y + (size_t)row * DMODEL;
#pragma unroll
    for (int i = 0; i < 4; ++i) {
        int d = t * 4 + i;
        float o = (v[i] - mu) * rstd * g[d] + bta[d];
        yr[d] = (bf16)o;
    }
}

// ---------------------------------------------------------------------------
// GEMM: C[M,N] = A[M,K](bf16) @ Bt[N,K](bf16)^T + bias(fp32)
// mode: 0 = bf16 out, 1 = bf16 out + exact GELU, 2 = fp32 out
// ---------------------------------------------------------------------------
#define BM 128
#define BN 128
#define BK 32
#define LDT 40

__global__ __launch_bounds__(256, 2) void gemm_bt(
    const bf16* __restrict__ A, const bf16* __restrict__ Bt,
    const float* __restrict__ bias, void* __restrict__ Cv,
    int M, int N, int K, int mode) {
    __shared__ bf16 sA[BM][LDT];
    __shared__ bf16 sB[BN][LDT];
    int t = threadIdx.x;
    int lane = t & 63, wave = t >> 6;
    int wr = wave >> 1, wc = wave & 1;
    int m0 = blockIdx.y * BM, n0 = blockIdx.x * BN;
    int ar = t >> 2;
    int ak = (t & 3) * 8;
    const bf16* Ap = A + (size_t)m0 * K;
    const bf16* Bp = Bt + (size_t)n0 * K;

    f32x4 acc[4][4];
#pragma unroll
    for (int i = 0; i < 4; ++i)
#pragma unroll
        for (int j = 0; j < 4; ++j) acc[i][j] = (f32x4){0.f, 0.f, 0.f, 0.f};

    int mq = lane & 15, kq = (lane >> 4) * 8;

    for (int k0 = 0; k0 < K; k0 += BK) {
        __syncthreads();
        *(uint4*)&sA[ar][ak]      = *(const uint4*)(Ap + (size_t)ar * K + k0 + ak);
        *(uint4*)&sA[ar + 64][ak] = *(const uint4*)(Ap + (size_t)(ar + 64) * K + k0 + ak);
        *(uint4*)&sB[ar][ak]      = *(const uint4*)(Bp + (size_t)ar * K + k0 + ak);
        *(uint4*)&sB[ar + 64][ak] = *(const uint4*)(Bp + (size_t)(ar + 64) * K + k0 + ak);
        __syncthreads();
        bf16x8 af[4], bfr[4];
#pragma unroll
        for (int i = 0; i < 4; ++i)
            af[i] = *(const bf16x8*)&sA[wr * 64 + i * 16 + mq][kq];
#pragma unroll
        for (int j = 0; j < 4; ++j)
            bfr[j] = *(const bf16x8*)&sB[wc * 64 + j * 16 + mq][kq];
#pragma unroll
        for (int i = 0; i < 4; ++i)
#pragma unroll
            for (int j = 0; j < 4; ++j)
                acc[i][j] = __builtin_amdgcn_mfma_f32_16x16x32_bf16(af[i], bfr[j], acc[i][j], 0, 0, 0);
    }

    int cq = lane & 15, rq = (lane >> 4) * 4;
#pragma unroll
    for (int i = 0; i < 4; ++i) {
        int row = m0 + wr * 64 + i * 16 + rq;
#pragma unroll
        for (int j = 0; j < 4; ++j) {
            int col = n0 + wc * 64 + j * 16 + cq;
            float bv = bias ? bias[col] : 0.0f;
#pragma unroll
            for (int r = 0; r < 4; ++r) {
                float v = acc[i][j][r] + bv;
                if (mode == 1) v = 0.5f * v * (1.0f + erff(v * 0.70710678118654752f));
                size_t idx = (size_t)(row + r) * N + col;
                if (mode == 2) ((float*)Cv)[idx] = v;
                else           ((bf16*)Cv)[idx] = (bf16)v;
            }
        }
    }
}

// ---------------------------------------------------------------------------
// MFMA flash attention. Block = one (b,h) x 64 Q rows; 4 waves x 16 rows.
// K-loop: 16 tiles of 64 keys. QK^T and PV via mfma_f32_16x16x32_bf16.
// Verified layouts: A m=lane&15,k=quad*8+j ; B n=lane&15 ; C/D col=lane&15,
// row=quad*4+reg. P goes C-layout -> LDS -> A-layout (m120 pattern).
// LDS: K[64][72] + Vt[64][72] + P[4][16][72] bf16 = 27.6 KB -> 5 blocks/CU.
// ---------------------------------------------------------------------------
#define LDK 72  // pad: 144B row stride (16B-aligned, breaks power-of-2)

__global__ __launch_bounds__(256, 2) void attn_mfma(const bf16* __restrict__ qkv,
                                                    bf16* __restrict__ ao) {
    __shared__ bf16 Klds[64][LDK];
    __shared__ bf16 Vtlds[64][LDK];     // [d][key]
    __shared__ bf16 Plds[4][16][LDK];   // per-wave P tile [qrow][key]
    int t = threadIdx.x, lane = t & 63, wave = t >> 6;
    int bh = blockIdx.y, bb = bh >> 4, h = bh & 15;
    int q0 = blockIdx.x * 64;
    const bf16* base = qkv + (size_t)bb * SEQ * 3072;
    int m = lane & 15, quad = lane >> 4;
    int kq = quad * 8;

    // Q A-frags (softmax scale 1/8 folded in; pow2 => exact in bf16)
    bf16x8 qf[2];
    {
        int qrow = q0 + wave * 16 + m;
        const bf16* p = base + (size_t)qrow * 3072 + h * 64;
#pragma unroll
        for (int c = 0; c < 2; ++c) {
            bf16x8 tmp = *(const bf16x8*)(p + c * 32 + kq);
#pragma unroll
            for (int j = 0; j < 8; ++j) qf[c][j] = (bf16)((float)tmp[j] * 0.125f);
        }
    }

    float m_run[4], l_run[4];
    f32x4 o_acc[4];
#pragma unroll
    for (int r = 0; r < 4; ++r) { m_run[r] = -3e38f; l_run[r] = 0.f; }
#pragma unroll
    for (int g = 0; g < 4; ++g) o_acc[g] = (f32x4){0.f, 0.f, 0.f, 0.f};

    int skey = t >> 3, sd0 = (t & 7) * 8;  // staging: 32 keys x 8 d per pass

    for (int kt = 0; kt < 16; ++kt) {
        __syncthreads();
        {
            const bf16* pk = base + (size_t)(kt * 64 + skey) * 3072 + 1024 + h * 64 + sd0;
            *(bf16x8*)&Klds[skey][sd0]      = *(const bf16x8*)pk;
            *(bf16x8*)&Klds[skey + 32][sd0] = *(const bf16x8*)(pk + 32 * 3072);
            const bf16* pv = base + (size_t)(kt * 64 + skey) * 3072 + 2048 + h * 64 + sd0;
            bf16x8 v0 = *(const bf16x8*)pv;
            bf16x8 v1 = *(const bf16x8*)(pv + 32 * 3072);
#pragma unroll
            for (int i = 0; i < 8; ++i) {
                Vtlds[sd0 + i][skey]      = v0[i];
                Vtlds[sd0 + i][skey + 32] = v1[i];
            }
        }
        __syncthreads();

        // ---- S = Q @ K^T for 4 groups of 16 keys ----
        f32x4 s[4];
#pragma unroll
        for (int g = 0; g < 4; ++g) {
            bf16x8 b0 = *(const bf16x8*)&Klds[g * 16 + m][kq];
            bf16x8 b1 = *(const bf16x8*)&Klds[g * 16 + m][32 + kq];
            s[g] = (f32x4){0.f, 0.f, 0.f, 0.f};
            s[g] = __builtin_amdgcn_mfma_f32_16x16x32_bf16(qf[0], b0, s[g], 0, 0, 0);
            s[g] = __builtin_amdgcn_mfma_f32_16x16x32_bf16(qf[1], b1, s[g], 0, 0, 0);
        }

        // ---- online softmax (rows = quad*4+r; reduce over lane bits 0-3) ----
#pragma unroll
        for (int r = 0; r < 4; ++r) {
            float mx = fmaxf(fmaxf(s[0][r], s[1][r]), fmaxf(s[2][r], s[3][r]));
#pragma unroll
            for (int msk = 1; msk < 16; msk <<= 1) mx = fmaxf(mx, __shfl_xor(mx, msk, 64));
            float m_new = fmaxf(m_run[r], mx);
            float alpha = __expf(m_run[r] - m_new);
            m_run[r] = m_new;
            float rowsum = 0.f;
#pragma unroll
            for (int g = 0; g < 4; ++g) {
                float p = __expf(s[g][r] - m_new);
                s[g][r] = p;  // reuse as P
                rowsum += p;
            }
#pragma unroll
            for (int msk = 1; msk < 16; msk <<= 1) rowsum += __shfl_xor(rowsum, msk, 64);
            l_run[r] = l_run[r] * alpha + rowsum;
#pragma unroll
            for (int g = 0; g < 4; ++g) o_acc[g][r] *= alpha;
        }

        // ---- P: C-layout -> LDS (A-layout source) ----
#pragma unroll
        for (int g = 0; g < 4; ++g)
#pragma unroll
            for (int r = 0; r < 4; ++r)
                Plds[wave][quad * 4 + r][g * 16 + m] = (bf16)s[g][r];

        // ---- O += P @ V ----
#pragma unroll
        for (int kc = 0; kc < 2; ++kc) {
            bf16x8 pf = *(const bf16x8*)&Plds[wave][m][kc * 32 + kq];
#pragma unroll
            for (int dg = 0; dg < 4; ++dg) {
                bf16x8 vf = *(const bf16x8*)&Vtlds[dg * 16 + m][kc * 32 + kq];
                o_acc[dg] = __builtin_amdgcn_mfma_f32_16x16x32_bf16(pf, vf, o_acc[dg], 0, 0, 0);
            }
        }
    }

    // ---- normalize + write ----
#pragma unroll
    for (int r = 0; r < 4; ++r) {
        int row = q0 + wave * 16 + quad * 4 + r;
        float rl = 1.0f / l_run[r];
        bf16* op = ao + ((size_t)bb * SEQ + row) * DMODEL + h * 64;
#pragma unroll
        for (int g = 0; g < 4; ++g) op[g * 16 + m] = (bf16)(o_acc[g][r] * rl);
    }
}

// ---------------------------------------------------------------------------
// kernel_launch — fp32 I/O, bf16 internal. ws peak 56 MiB; d_out (32 MB) used
// as scratch (xn/ao in [0,16M), x2n in [16M,32M), final fp32 out last).
// ---------------------------------------------------------------------------
extern "C" void kernel_launch(void* const* d_in, const int* in_sizes, int n_in,
                              void* d_out, int out_size, void* d_ws, size_t ws_size,
                              hipStream_t stream) {
    const float* x     = (const float*)d_in[0];
    const float* ln1_g = (const float*)d_in[1];
    const float* ln1_b = (const float*)d_in[2];
    const float* w_qkv = (const float*)d_in[3];
    const float* w_out = (const float*)d_in[4];
    const float* b_out = (const float*)d_in[5];
    const float* ln2_g = (const float*)d_in[6];
    const float* ln2_b = (const float*)d_in[7];
    const float* w1    = (const float*)d_in[8];
    const float* b1    = (const float*)d_in[9];
    const float* w2    = (const float*)d_in[10];
    const float* b2    = (const float*)d_in[11];
    float* out = (float*)d_out;
    char* ws = (char*)d_ws;
    char* outc = (char*)d_out;

    bf16* wqkvT = (bf16*)(ws + (0ull << 20));
    bf16* woutT = (bf16*)(ws + (6ull << 20));
    bf16* qkv   = (bf16*)(ws + (8ull << 20));
    bf16* w1T   = (bf16*)(ws + (8ull << 20));    // over dead qkv (after attn)
    bf16* w2T   = (bf16*)(ws + (16ull << 20));   // over dead qkv (after attn)
    float* x2   = (float*)(ws + (24ull << 20));  // over dead qkv (after attn)
    bf16* hbuf  = (bf16*)(ws + (24ull << 20));   // over dead x2 (after ln2)
    bf16* xn    = (bf16*)(outc + 0);             // d_out as scratch
    bf16* ao    = (bf16*)(outc + 0);             // xn dead
    bf16* x2n   = (bf16*)(outc + (16ull << 20)); // upper half of d_out

    dim3 tb(32, 8);
    transpose_f2b<<<dim3(3072 / 32, 1024 / 32), tb, 0, stream>>>(w_qkv, wqkvT, 1024, 3072);
    transpose_f2b<<<dim3(1024 / 32, 1024 / 32), tb, 0, stream>>>(w_out, woutT, 1024, 1024);

    ln_f2b<<<8192, 256, 0, stream>>>(x, ln1_g, ln1_b, xn);
    gemm_bt<<<dim3(3072 / 128, 8192 / 128), 256, 0, stream>>>(xn, wqkvT, nullptr, qkv,
                                                              8192, 3072, 1024, 0);
    attn_mfma<<<dim3(SEQ / 64, 128), 256, 0, stream>>>(qkv, ao);

    transpose_f2b<<<dim3(4096 / 32, 1024 / 32), tb, 0, stream>>>(w1, w1T, 1024, 4096);
    transpose_f2b<<<dim3(1024 / 32, 4096 / 32), tb, 0, stream>>>(w2, w2T, 4096, 1024);

    gemm_bt<<<dim3(1024 / 128, 8192 / 128), 256, 0, stream>>>(ao, woutT, b_out, x2,
                                                              8192, 1024, 1024, 2);
    ln_f2b<<<8192, 256, 0, stream>>>(x2, ln2_g, ln2_b, x2n);

    for (int c = 0; c < 2; ++c) {
        const bf16* a1 = x2n + (size_t)c * 4096 * 1024;
        float* oc = out + (size_t)c * 4096 * 1024;
        gemm_bt<<<dim3(4096 / 128, 4096 / 128), 256, 0, stream>>>(a1, w1T, b1, hbuf,
                                                                  4096, 4096, 1024, 1);
        gemm_bt<<<dim3(1024 / 128, 4096 / 128), 256, 0, stream>>>(hbuf, w2T, b2, oc,
                                                                  4096, 1024, 4096, 2);
    }
}

// Round 5
// 650.000 us; speedup vs baseline: 5.0589x; 1.0776x over previous
//
#include <hip/hip_runtime.h>
#include <hip/hip_bf16.h>
#include <math.h>

typedef __bf16 bf16;
typedef __bf16 bf16x8 __attribute__((ext_vector_type(8)));
typedef float f32x4 __attribute__((ext_vector_type(4)));

#define SEQ 1024
#define DMODEL 1024

// async global->LDS DMA, 16B per lane, dest = wave-uniform base + lane*16
__device__ __forceinline__ void gld_lds16(const bf16* g, bf16* l) {
    __builtin_amdgcn_global_load_lds(
        (const __attribute__((address_space(1))) unsigned int*)g,
        (__attribute__((address_space(3))) unsigned int*)l, 16, 0, 0);
}

// ---------------------------------------------------------------------------
// Fused transpose + fp32->bf16 convert: out[n*K + k] = (bf16)in[k*N + n]
// ---------------------------------------------------------------------------
__global__ void transpose_f2b(const float* __restrict__ in, bf16* __restrict__ out,
                              int K, int N) {
    __shared__ float tile[32][33];
    int n0 = blockIdx.x * 32, k0 = blockIdx.y * 32;
    int tx = threadIdx.x, ty = threadIdx.y;
#pragma unroll
    for (int i = 0; i < 4; ++i) {
        int kk = ty + i * 8;
        tile[kk][tx] = in[(size_t)(k0 + kk) * N + n0 + tx];
    }
    __syncthreads();
#pragma unroll
    for (int i = 0; i < 4; ++i) {
        int nn = ty + i * 8;
        out[(size_t)(n0 + nn) * K + k0 + tx] = (bf16)tile[tx][nn];
    }
}

// ---------------------------------------------------------------------------
// LayerNorm: fp32 in -> bf16 out. One row (D=1024) per 256-thread block.
// ---------------------------------------------------------------------------
__global__ void ln_f2b(const float* __restrict__ x, const float* __restrict__ g,
                       const float* __restrict__ bta, bf16* __restrict__ y) {
    int row = blockIdx.x, t = threadIdx.x;
    const float* xr = x + (size_t)row * DMODEL;
    float v[4];
#pragma unroll
    for (int i = 0; i < 4; ++i) v[i] = xr[t * 4 + i];
    float s = v[0] + v[1] + v[2] + v[3];
    float s2 = v[0] * v[0] + v[1] * v[1] + v[2] * v[2] + v[3] * v[3];
#pragma unroll
    for (int off = 32; off > 0; off >>= 1) {
        s += __shfl_down(s, off, 64);
        s2 += __shfl_down(s2, off, 64);
    }
    __shared__ float ws1[4], ws2[4];
    __shared__ float mu_s, rstd_s;
    int lane = t & 63, wv = t >> 6;
    if (lane == 0) { ws1[wv] = s; ws2[wv] = s2; }
    __syncthreads();
    if (t == 0) {
        float S1 = ws1[0] + ws1[1] + ws1[2] + ws1[3];
        float S2 = ws2[0] + ws2[1] + ws2[2] + ws2[3];
        float mu = S1 * (1.0f / DMODEL);
        float var = S2 * (1.0f / DMODEL) - mu * mu;
        mu_s = mu;
        rstd_s = rsqrtf(var + 1e-5f);
    }
    __syncthreads();
    float mu = mu_s, rstd = rstd_s;
    bf16* yr = y + (size_t)row * DMODEL;
#pragma unroll
    for (int i = 0; i < 4; ++i) {
        int d = t * 4 + i;
        float o = (v[i] - mu) * rstd * g[d] + bta[d];
        yr[d] = (bf16)o;
    }
}

// ---------------------------------------------------------------------------
// GEMM: C[M,N] = A[M,K](bf16) @ Bt[N,K](bf16)^T + bias(fp32)
// mode: 0 = bf16 out, 1 = bf16 out + exact GELU, 2 = fp32 out
// m97 pattern: global_load_lds width-16 staging into UNPADDED LDS tiles with
// XOR-16B-chunk swizzle (physical chunk = logical ^ (row&3), folded into the
// per-lane global src address). Fragment ds_read_b128 then hits 4-way
// (1.58x) instead of padded 2-way, but staging is pure DMA (no VGPR trip).
// ---------------------------------------------------------------------------
#define BM 128
#define BN 128
#define BK 32

__global__ __launch_bounds__(256, 2) void gemm_bt(
    const bf16* __restrict__ A, const bf16* __restrict__ Bt,
    const float* __restrict__ bias, void* __restrict__ Cv,
    int M, int N, int K, int mode) {
    __shared__ bf16 sA[BM * BK];   // row-major, 64B rows, chunk-swizzled
    __shared__ bf16 sB[BN * BK];
    int t = threadIdx.x;
    int lane = t & 63, wave = t >> 6;
    int wr = wave >> 1, wc = wave & 1;
    int m0 = blockIdx.y * BM, n0 = blockIdx.x * BN;
    const bf16* Ap = A + (size_t)m0 * K;
    const bf16* Bp = Bt + (size_t)n0 * K;

    // staging: wave w covers LDS rows [w*16, w*16+16) (+64 on issue 2)
    int srow = wave * 16 + (lane >> 2);
    int schunk = lane & 3;
    int gcoff = (schunk ^ (srow & 3)) * 8;   // swizzled logical chunk (elems)
    const bf16* gA0 = Ap + (size_t)srow * K + gcoff;
    const bf16* gA1 = Ap + (size_t)(srow + 64) * K + gcoff;  // (srow+64)&3 == srow&3
    const bf16* gB0 = Bp + (size_t)srow * K + gcoff;
    const bf16* gB1 = Bp + (size_t)(srow + 64) * K + gcoff;
    bf16* lA0 = sA + wave * 512;
    bf16* lA1 = sA + 2048 + wave * 512;
    bf16* lB0 = sB + wave * 512;
    bf16* lB1 = sB + 2048 + wave * 512;

    f32x4 acc[4][4];
#pragma unroll
    for (int i = 0; i < 4; ++i)
#pragma unroll
        for (int j = 0; j < 4; ++j) acc[i][j] = (f32x4){0.f, 0.f, 0.f, 0.f};

    int mq = lane & 15, quad = lane >> 4;
    int csw = (quad ^ (mq & 3)) * 8;   // physical chunk holding logical chunk `quad`

    for (int k0 = 0; k0 < K; k0 += BK) {
        __syncthreads();
        gld_lds16(gA0 + k0, lA0);
        gld_lds16(gA1 + k0, lA1);
        gld_lds16(gB0 + k0, lB0);
        gld_lds16(gB1 + k0, lB1);
        __syncthreads();
        bf16x8 af[4], bfr[4];
#pragma unroll
        for (int i = 0; i < 4; ++i)
            af[i] = *(const bf16x8*)&sA[(wr * 64 + i * 16 + mq) * BK + csw];
#pragma unroll
        for (int j = 0; j < 4; ++j)
            bfr[j] = *(const bf16x8*)&sB[(wc * 64 + j * 16 + mq) * BK + csw];
#pragma unroll
        for (int i = 0; i < 4; ++i)
#pragma unroll
            for (int j = 0; j < 4; ++j)
                acc[i][j] = __builtin_amdgcn_mfma_f32_16x16x32_bf16(af[i], bfr[j], acc[i][j], 0, 0, 0);
    }

    int cq = lane & 15, rq = (lane >> 4) * 4;
#pragma unroll
    for (int i = 0; i < 4; ++i) {
        int row = m0 + wr * 64 + i * 16 + rq;
#pragma unroll
        for (int j = 0; j < 4; ++j) {
            int col = n0 + wc * 64 + j * 16 + cq;
            float bv = bias ? bias[col] : 0.0f;
#pragma unroll
            for (int r = 0; r < 4; ++r) {
                float v = acc[i][j][r] + bv;
                if (mode == 1) v = 0.5f * v * (1.0f + erff(v * 0.70710678118654752f));
                size_t idx = (size_t)(row + r) * N + col;
                if (mode == 2) ((float*)Cv)[idx] = v;
                else           ((bf16*)Cv)[idx] = (bf16)v;
            }
        }
    }
}

// ---------------------------------------------------------------------------
// MFMA flash attention. Block = one (b,h) x 64 Q rows; 4 waves x 16 rows.
// Vt staging uses rotated store order j=(i+(t&7))&7: banks 36j+skey/2 mod 32
// are distinct per d-group -> ~2-way (was structural 16-way, 3.88e7 cycles).
// ---------------------------------------------------------------------------
#define LDK 72

__global__ __launch_bounds__(256, 2) void attn_mfma(const bf16* __restrict__ qkv,
                                                    bf16* __restrict__ ao) {
    __shared__ bf16 Klds[64][LDK];
    __shared__ bf16 Vtlds[64][LDK];     // [d][key]
    __shared__ bf16 Plds[4][16][LDK];
    int t = threadIdx.x, lane = t & 63, wave = t >> 6;
    int bh = blockIdx.y, bb = bh >> 4, h = bh & 15;
    int q0 = blockIdx.x * 64;
    const bf16* base = qkv + (size_t)bb * SEQ * 3072;
    int m = lane & 15, quad = lane >> 4;
    int kq = quad * 8;

    bf16x8 qf[2];
    {
        int qrow = q0 + wave * 16 + m;
        const bf16* p = base + (size_t)qrow * 3072 + h * 64;
#pragma unroll
        for (int c = 0; c < 2; ++c) {
            bf16x8 tmp = *(const bf16x8*)(p + c * 32 + kq);
#pragma unroll
            for (int j = 0; j < 8; ++j) qf[c][j] = (bf16)((float)tmp[j] * 0.125f);
        }
    }

    float m_run[4], l_run[4];
    f32x4 o_acc[4];
#pragma unroll
    for (int r = 0; r < 4; ++r) { m_run[r] = -3e38f; l_run[r] = 0.f; }
#pragma unroll
    for (int g = 0; g < 4; ++g) o_acc[g] = (f32x4){0.f, 0.f, 0.f, 0.f};

    int skey = t >> 3, sd0 = (t & 7) * 8;
    int rot = t & 7;

    for (int kt = 0; kt < 16; ++kt) {
        __syncthreads();
        {
            const bf16* pk = base + (size_t)(kt * 64 + skey) * 3072 + 1024 + h * 64 + sd0;
            *(bf16x8*)&Klds[skey][sd0]      = *(const bf16x8*)pk;
            *(bf16x8*)&Klds[skey + 32][sd0] = *(const bf16x8*)(pk + 32 * 3072);
            const bf16* pv = base + (size_t)(kt * 64 + skey) * 3072 + 2048 + h * 64 + sd0;
            bf16x8 v0 = *(const bf16x8*)pv;
            bf16x8 v1 = *(const bf16x8*)(pv + 32 * 3072);
#pragma unroll
            for (int ii = 0; ii < 8; ++ii) {
                int j = (ii + rot) & 7;
                Vtlds[sd0 + j][skey]      = v0[j];
                Vtlds[sd0 + j][skey + 32] = v1[j];
            }
        }
        __syncthreads();

        f32x4 s[4];
#pragma unroll
        for (int g = 0; g < 4; ++g) {
            bf16x8 b0 = *(const bf16x8*)&Klds[g * 16 + m][kq];
            bf16x8 b1 = *(const bf16x8*)&Klds[g * 16 + m][32 + kq];
            s[g] = (f32x4){0.f, 0.f, 0.f, 0.f};
            s[g] = __builtin_amdgcn_mfma_f32_16x16x32_bf16(qf[0], b0, s[g], 0, 0, 0);
            s[g] = __builtin_amdgcn_mfma_f32_16x16x32_bf16(qf[1], b1, s[g], 0, 0, 0);
        }

#pragma unroll
        for (int r = 0; r < 4; ++r) {
            float mx = fmaxf(fmaxf(s[0][r], s[1][r]), fmaxf(s[2][r], s[3][r]));
#pragma unroll
            for (int msk = 1; msk < 16; msk <<= 1) mx = fmaxf(mx, __shfl_xor(mx, msk, 64));
            float m_new = fmaxf(m_run[r], mx);
            float alpha = __expf(m_run[r] - m_new);
            m_run[r] = m_new;
            float rowsum = 0.f;
#pragma unroll
            for (int g = 0; g < 4; ++g) {
                float p = __expf(s[g][r] - m_new);
                s[g][r] = p;
                rowsum += p;
            }
#pragma unroll
            for (int msk = 1; msk < 16; msk <<= 1) rowsum += __shfl_xor(rowsum, msk, 64);
            l_run[r] = l_run[r] * alpha + rowsum;
#pragma unroll
            for (int g = 0; g < 4; ++g) o_acc[g][r] *= alpha;
        }

#pragma unroll
        for (int g = 0; g < 4; ++g)
#pragma unroll
            for (int r = 0; r < 4; ++r)
                Plds[wave][quad * 4 + r][g * 16 + m] = (bf16)s[g][r];

#pragma unroll
        for (int kc = 0; kc < 2; ++kc) {
            bf16x8 pf = *(const bf16x8*)&Plds[wave][m][kc * 32 + kq];
#pragma unroll
            for (int dg = 0; dg < 4; ++dg) {
                bf16x8 vf = *(const bf16x8*)&Vtlds[dg * 16 + m][kc * 32 + kq];
                o_acc[dg] = __builtin_amdgcn_mfma_f32_16x16x32_bf16(pf, vf, o_acc[dg], 0, 0, 0);
            }
        }
    }

#pragma unroll
    for (int r = 0; r < 4; ++r) {
        int row = q0 + wave * 16 + quad * 4 + r;
        float rl = 1.0f / l_run[r];
        bf16* op = ao + ((size_t)bb * SEQ + row) * DMODEL + h * 64;
#pragma unroll
        for (int g = 0; g < 4; ++g) op[g * 16 + m] = (bf16)(o_acc[g][r] * rl);
    }
}

// ---------------------------------------------------------------------------
// kernel_launch — fp32 I/O, bf16 internal. ws peak 56 MiB; d_out (32 MB) used
// as scratch (xn/ao in [0,16M), x2n in [16M,32M), final fp32 out last).
// ---------------------------------------------------------------------------
extern "C" void kernel_launch(void* const* d_in, const int* in_sizes, int n_in,
                              void* d_out, int out_size, void* d_ws, size_t ws_size,
                              hipStream_t stream) {
    const float* x     = (const float*)d_in[0];
    const float* ln1_g = (const float*)d_in[1];
    const float* ln1_b = (const float*)d_in[2];
    const float* w_qkv = (const float*)d_in[3];
    const float* w_out = (const float*)d_in[4];
    const float* b_out = (const float*)d_in[5];
    const float* ln2_g = (const float*)d_in[6];
    const float* ln2_b = (const float*)d_in[7];
    const float* w1    = (const float*)d_in[8];
    const float* b1    = (const float*)d_in[9];
    const float* w2    = (const float*)d_in[10];
    const float* b2    = (const float*)d_in[11];
    float* out = (float*)d_out;
    char* ws = (char*)d_ws;
    char* outc = (char*)d_out;

    bf16* wqkvT = (bf16*)(ws + (0ull << 20));
    bf16* woutT = (bf16*)(ws + (6ull << 20));
    bf16* qkv   = (bf16*)(ws + (8ull << 20));
    bf16* w1T   = (bf16*)(ws + (8ull << 20));    // over dead qkv (after attn)
    bf16* w2T   = (bf16*)(ws + (16ull << 20));   // over dead qkv (after attn)
    float* x2   = (float*)(ws + (24ull << 20));  // over dead qkv (after attn)
    bf16* hbuf  = (bf16*)(ws + (24ull << 20));   // over dead x2 (after ln2)
    bf16* xn    = (bf16*)(outc + 0);             // d_out as scratch
    bf16* ao    = (bf16*)(outc + 0);             // xn dead
    bf16* x2n   = (bf16*)(outc + (16ull << 20)); // upper half of d_out

    dim3 tb(32, 8);
    transpose_f2b<<<dim3(3072 / 32, 1024 / 32), tb, 0, stream>>>(w_qkv, wqkvT, 1024, 3072);
    transpose_f2b<<<dim3(1024 / 32, 1024 / 32), tb, 0, stream>>>(w_out, woutT, 1024, 1024);

    ln_f2b<<<8192, 256, 0, stream>>>(x, ln1_g, ln1_b, xn);
    gemm_bt<<<dim3(3072 / 128, 8192 / 128), 256, 0, stream>>>(xn, wqkvT, nullptr, qkv,
                                                              8192, 3072, 1024, 0);
    attn_mfma<<<dim3(SEQ / 64, 128), 256, 0, stream>>>(qkv, ao);

    transpose_f2b<<<dim3(4096 / 32, 1024 / 32), tb, 0, stream>>>(w1, w1T, 1024, 4096);
    transpose_f2b<<<dim3(1024 / 32, 4096 / 32), tb, 0, stream>>>(w2, w2T, 4096, 1024);

    gemm_bt<<<dim3(1024 / 128, 8192 / 128), 256, 0, stream>>>(ao, woutT, b_out, x2,
                                                              8192, 1024, 1024, 2);
    ln_f2b<<<8192, 256, 0, stream>>>(x2, ln2_g, ln2_b, x2n);

    for (int c = 0; c < 2; ++c) {
        const bf16* a1 = x2n + (size_t)c * 4096 * 1024;
        float* oc = out + (size_t)c * 4096 * 1024;
        gemm_bt<<<dim3(4096 / 128, 4096 / 128), 256, 0, stream>>>(a1, w1T, b1, hbuf,
                                                                  4096, 4096, 1024, 1);
        gemm_bt<<<dim3(1024 / 128, 4096 / 128), 256, 0, stream>>>(hbuf, w2T, b2, oc,
                                                                  4096, 1024, 4096, 2);
    }
}